// Round 6
// baseline (260.709 us; speedup 1.0000x reference)
//
#include <hip/hip_runtime.h>
#include <stdint.h>
#include <stddef.h>

// Problem constants (B=4, L=1024, D=768, H=6, DH=128)
#define BB 4
#define LL 1024
#define DD 768
#define HH 6
#define DHH 128
#define EPS 1e-5f
#define LOG2E 1.44269504088896f

// Output layout (fp32 elements, concatenated in return order):
//   co : (B,H,L,L) = 25165824
//   w  : (B,L,1)   = 4096
//   Vh : (B,H,L,DH)= 3145728
#define CO_ELEMS 25165824
#define W_ELEMS  4096

// ws layout (fp32 elements), ~21.2 MB. All deterministic writes, no atomics.
#define OFF_Q2  0           // 24576
#define OFF_K2  24576       // 24576
#define OFF_WC  49152       // 24576  final col sums
#define OFF_SP  73728       // 48     per-bh {sumS,sumS2} analytic moments
#define OFF_AC  79872       // 16     a1[0..7], c1[8..15]
#define OFF_SS  79888       // 192    BN2 (sum,sumsq) block partials
#define OFF_WP  81920       // 64*24*1024 = 1572864 col-sum half-strip partials
#define OFF_GP  1654784     // 2*24*8*36*256 = 3538944 Gram tile chunk partials
#define OFF_MS1 5193728     // 2*24*8*128 = 49152  per-d sum partials
#define OFF_MS2 5242880     // 49152               per-d weighted-sum partials
// total 5292032 floats = 21.2 MB

typedef __attribute__((ext_vector_type(8))) short short8;
typedef __attribute__((ext_vector_type(4))) float f32x4;

// load 8 contiguous fp32, truncate to bf16 fragment
__device__ __forceinline__ short8 ld_bf8(const float* __restrict__ p) {
    const float4 a = *(const float4*)(p);
    const float4 b = *(const float4*)(p + 4);
    short8 r;
    r[0] = (short)(__float_as_uint(a.x) >> 16);
    r[1] = (short)(__float_as_uint(a.y) >> 16);
    r[2] = (short)(__float_as_uint(a.z) >> 16);
    r[3] = (short)(__float_as_uint(a.w) >> 16);
    r[4] = (short)(__float_as_uint(b.x) >> 16);
    r[5] = (short)(__float_as_uint(b.y) >> 16);
    r[6] = (short)(__float_as_uint(b.z) >> 16);
    r[7] = (short)(__float_as_uint(b.w) >> 16);
    return r;
}

__device__ __forceinline__ short8 pack_bf8(float4 a, float4 b) {
    short8 r;
    r[0] = (short)(__float_as_uint(a.x) >> 16);
    r[1] = (short)(__float_as_uint(a.y) >> 16);
    r[2] = (short)(__float_as_uint(a.z) >> 16);
    r[3] = (short)(__float_as_uint(a.w) >> 16);
    r[4] = (short)(__float_as_uint(b.x) >> 16);
    r[5] = (short)(__float_as_uint(b.y) >> 16);
    r[6] = (short)(__float_as_uint(b.z) >> 16);
    r[7] = (short)(__float_as_uint(b.w) >> 16);
    return r;
}

// ---- PREP (fused rownorm + msums + gram partials + Vh copy).
// grid (8, 24, 3): z=0 Q-side, z=1 K-side, z=2 Vh copy chunk.
__global__ __launch_bounds__(256) void k_gram(
        const float* __restrict__ Q, const float* __restrict__ K,
        const float* __restrict__ V,
        float* __restrict__ ws, float* __restrict__ gramP,
        float* __restrict__ ms1, float* __restrict__ ms2,
        float* __restrict__ vh) {
    const int ic = blockIdx.x;            // 0..7
    const int bh = blockIdx.y;            // 0..23
    const int which = blockIdx.z;         // 0=Q, 1=K, 2=Vh
    const int b = bh / HH, h = bh - b * HH;
    const int t = threadIdx.x;

    if (which == 2) {                     // Vh copy: 128 rows x 128 dh
        const float* srcv = V + (size_t)b * LL * DD + h * DHH;
        float* dstv = vh + ((size_t)bh * LL + (size_t)ic * 128) * DHH;
#pragma unroll
        for (int p = 0; p < 16; p++) {
            const int idx = p * 256 + t;          // 0..4095
            const int row = idx >> 5, d4 = idx & 31;
            f32x4 v = *(const f32x4*)(srcv + (size_t)(ic * 128 + row) * DD + d4 * 4);
            __builtin_nontemporal_store(v, (f32x4*)(dstv + (size_t)row * DHH + d4 * 4));
        }
        return;
    }

    const float* src = (which ? K : Q) + (size_t)b * LL * DD + h * DHH;
    float* sqout = ws + (which ? OFF_K2 : OFF_Q2) + bh * 1024 + ic * 128;

    const int lane = t & 63, wv = t >> 6;
    const int lm = lane & 15, quad = lane >> 4;

    __shared__ float tileT[128][129];     // [d][i] truncated fp32
    __shared__ float q2loc[128];

    // ---- stage + per-row sq-norm
    const int ig = t >> 5;                 // 0..7 (row subgroup)
    const int d0 = (t & 31) * 4;
#pragma unroll 4
    for (int p = 0; p < 16; p++) {
        const int i_loc = p * 8 + ig;
        float4 v = *(const float4*)(src + (size_t)(ic * 128 + i_loc) * DD + d0);
        tileT[d0 + 0][i_loc] = __uint_as_float(__float_as_uint(v.x) & 0xffff0000u);
        tileT[d0 + 1][i_loc] = __uint_as_float(__float_as_uint(v.y) & 0xffff0000u);
        tileT[d0 + 2][i_loc] = __uint_as_float(__float_as_uint(v.z) & 0xffff0000u);
        tileT[d0 + 3][i_loc] = __uint_as_float(__float_as_uint(v.w) & 0xffff0000u);
        float s = v.x * v.x + v.y * v.y + v.z * v.z + v.w * v.w;
#pragma unroll
        for (int off = 1; off < 32; off <<= 1) s += __shfl_xor(s, off);
        if ((t & 31) == 0) { q2loc[i_loc] = s; sqout[i_loc] = s; }
    }
    __syncthreads();

    // ---- per-d sums over this chunk
    if (t < 128) {
        float s1 = 0.f, s2 = 0.f;
#pragma unroll 8
        for (int i = 0; i < 128; i++) {
            float v = tileT[t][i];
            s1 += v;
            s2 += v * q2loc[i];
        }
        const size_t mo = ((size_t)(which * 24 + bh) * 8 + ic) * 128 + t;
        ms1[mo] = s1;
        ms2[mo] = s2;
    }

    // ---- Gram tile partials: pairs pi with pi%4==wv (9 per wave)
    const size_t gbase = ((size_t)(which * 24 + bh) * 8 + ic) * 9216;
    int pi = 0;
    for (int dt = 0; dt < 8; dt++) {
        for (int et = dt; et < 8; et++, pi++) {
            if ((pi & 3) != wv) continue;
            f32x4 acc = (f32x4)(0.0f);
#pragma unroll
            for (int kk = 0; kk < 4; kk++) {
                const int i0 = kk * 32 + quad * 8;
                const float* pa = &tileT[dt * 16 + lm][i0];
                const float* pb = &tileT[et * 16 + lm][i0];
                short8 af, bf;
#pragma unroll
                for (int e = 0; e < 8; e++) {
                    af[e] = (short)(__float_as_uint(pa[e]) >> 16);
                    bf[e] = (short)(__float_as_uint(pb[e]) >> 16);
                }
                acc = __builtin_amdgcn_mfma_f32_16x16x32_bf16(af, bf, acc, 0, 0, 0);
            }
            if (dt != et && which == 0) {
                acc[0] *= 2.f; acc[1] *= 2.f; acc[2] *= 2.f; acc[3] *= 2.f;
            }
            *(f32x4*)&gramP[gbase + (size_t)pi * 256 + lane * 4] = acc;
        }
    }
}

// ---- assemble analytic BN1 moments per bh (1024 thr: 16 waves hide L3 lat):
// sumS  = 2*dA - 1024*(Sq2+Sk2)
// sumS2 = 4*GG + 1024*(Sq2sq+Sk2sq) + 2*Sq2*Sk2 - 4*(dBq+dBk)
__global__ __launch_bounds__(1024) void k_stats3(
        const float* __restrict__ ms1, const float* __restrict__ ms2,
        const float* __restrict__ gramP,
        const float* __restrict__ q2, const float* __restrict__ k2,
        float* __restrict__ statsP) {
    const int bh = blockIdx.x;
    const int t = threadIdx.x, lane = t & 63, w = t >> 6;   // w 0..15
    __shared__ float sQ[128], sK[128], sQq2[128], sKk2[128];
    __shared__ float sred[16][4];
    __shared__ float gred[16];

    if (t < 256) {   // per-d chunk reduce
        const int d = t & 127, which = t >> 7;
        const float* p1 = ms1 + (size_t)(which * 24 + bh) * 1024 + d;
        const float* p2 = ms2 + (size_t)(which * 24 + bh) * 1024 + d;
        float s1 = 0.f, s2 = 0.f;
#pragma unroll
        for (int ic = 0; ic < 8; ic++) { s1 += p1[ic * 128]; s2 += p2[ic * 128]; }
        if (which) { sK[d] = s1; sKk2[d] = s2; }
        else       { sQ[d] = s1; sQq2[d] = s2; }
    }
    if (t >= 512 && t < 768) {   // scalar sums of q2/k2 and squares (waves 8-11)
        const int tt = t - 512;
        f32x4 qv = *(const f32x4*)(q2 + bh * 1024 + tt * 4);
        f32x4 kv = *(const f32x4*)(k2 + bh * 1024 + tt * 4);
        float p0 = qv[0] + qv[1] + qv[2] + qv[3];
        float p1 = qv[0]*qv[0] + qv[1]*qv[1] + qv[2]*qv[2] + qv[3]*qv[3];
        float p2 = kv[0] + kv[1] + kv[2] + kv[3];
        float p3 = kv[0]*kv[0] + kv[1]*kv[1] + kv[2]*kv[2] + kv[3]*kv[3];
#pragma unroll
        for (int off = 1; off < 64; off <<= 1) {
            p0 += __shfl_xor(p0, off); p1 += __shfl_xor(p1, off);
            p2 += __shfl_xor(p2, off); p3 += __shfl_xor(p3, off);
        }
        if (lane == 0) { sred[w][0] = p0; sred[w][1] = p1; sred[w][2] = p2; sred[w][3] = p3; }
    }
    {   // GG: flat over 36*256=9216 elems, chunks reduced BEFORE the product
        const float* gq = gramP + (size_t)(0 * 24 + bh) * 8 * 9216;
        const float* gk = gramP + (size_t)(1 * 24 + bh) * 8 * 9216;
        float gg = 0.f;
#pragma unroll
        for (int it = 0; it < 9; it++) {
            const int f = it * 1024 + t;
            float a = 0.f, c = 0.f;
#pragma unroll
            for (int icc = 0; icc < 8; icc++) {
                a += gq[(size_t)icc * 9216 + f];
                c += gk[(size_t)icc * 9216 + f];
            }
            gg += a * c;
        }
#pragma unroll
        for (int off = 1; off < 64; off <<= 1) gg += __shfl_xor(gg, off);
        if (lane == 0) gred[w] = gg;
    }
    __syncthreads();
    if (t < 64) {
        float dA  = sQ[t] * sK[t] + sQ[t + 64] * sK[t + 64];
        float dBq = sQq2[t] * sK[t] + sQq2[t + 64] * sK[t + 64];
        float dBk = sQ[t] * sKk2[t] + sQ[t + 64] * sKk2[t + 64];
#pragma unroll
        for (int off = 1; off < 64; off <<= 1) {
            dA += __shfl_xor(dA, off); dBq += __shfl_xor(dBq, off); dBk += __shfl_xor(dBk, off);
        }
        if (t == 0) {
            float SQ2   = sred[8][0] + sred[9][0] + sred[10][0] + sred[11][0];
            float SQ2SQ = sred[8][1] + sred[9][1] + sred[10][1] + sred[11][1];
            float SK2   = sred[8][2] + sred[9][2] + sred[10][2] + sred[11][2];
            float SK2SQ = sred[8][3] + sred[9][3] + sred[10][3] + sred[11][3];
            float GG = 0.f;
#pragma unroll
            for (int i = 0; i < 16; i++) GG += gred[i];
            float sumS  = 2.f * dA - 1024.f * (SQ2 + SK2);
            float sumS2 = 4.f * GG + 1024.f * (SQ2SQ + SK2SQ) + 2.f * SQ2 * SK2 - 4.f * (dBq + dBk);
            statsP[bh * 2]     = sumS;
            statsP[bh * 2 + 1] = sumS2;
        }
    }
}

// --------------------------------------------- BN1 stats -> ac
__global__ void k_stats2(const float* __restrict__ statsP,
                         const float* __restrict__ g1, const float* __restrict__ b1,
                         float* __restrict__ ac) {
    const int t = threadIdx.x;
    if (t < HH) {
        float T1 = 0.f, T2 = 0.f;
#pragma unroll
        for (int b = 0; b < 4; b++) {
            T1 += statsP[(b * HH + t) * 2];
            T2 += statsP[(b * HH + t) * 2 + 1];
        }
        const float N = 4194304.f;                 // 4*1024*1024
        float m_ = T1 / N;
        float var = fmaxf(T2 / N - m_ * m_, 0.0f);
        float r = rsqrtf(var + EPS);
        float a = r * g1[t];
        ac[t] = a;
        ac[8 + t] = b1[t] - m_ * a;
    }
}

// K-tile load into a NAMED register buffer (all indices compile-time const)
#define KLOAD(buf, jtv) do {                                                   \
    const float* _p = Kb + (size_t)(jw + (jtv) * 16 + lm) * DD + quad * 8;     \
    buf##0 = *(const float4*)(_p);        buf##1 = *(const float4*)(_p + 4);   \
    buf##2 = *(const float4*)(_p + 32);   buf##3 = *(const float4*)(_p + 36);  \
    buf##4 = *(const float4*)(_p + 64);   buf##5 = *(const float4*)(_p + 68);  \
    buf##6 = *(const float4*)(_p + 96);   buf##7 = *(const float4*)(_p + 100); \
} while (0)

// one jt's MFMA + BN + exp2 + LDS-store, consuming a named buffer
#define KCOMP(buf, jtv) do {                                                   \
    short8 kf0 = pack_bf8(buf##0, buf##1);                                     \
    short8 kf1 = pack_bf8(buf##2, buf##3);                                     \
    short8 kf2 = pack_bf8(buf##4, buf##5);                                     \
    short8 kf3 = pack_bf8(buf##6, buf##7);                                     \
    f32x4 acc0 = (f32x4)(0.0f), acc1 = (f32x4)(0.0f);                          \
    acc0 = __builtin_amdgcn_mfma_f32_16x16x32_bf16(kf0, qf[0][0], acc0, 0, 0, 0); \
    acc1 = __builtin_amdgcn_mfma_f32_16x16x32_bf16(kf0, qf[1][0], acc1, 0, 0, 0); \
    acc0 = __builtin_amdgcn_mfma_f32_16x16x32_bf16(kf1, qf[0][1], acc0, 0, 0, 0); \
    acc1 = __builtin_amdgcn_mfma_f32_16x16x32_bf16(kf1, qf[1][1], acc1, 0, 0, 0); \
    acc0 = __builtin_amdgcn_mfma_f32_16x16x32_bf16(kf2, qf[0][2], acc0, 0, 0, 0); \
    acc1 = __builtin_amdgcn_mfma_f32_16x16x32_bf16(kf2, qf[1][2], acc1, 0, 0, 0); \
    acc0 = __builtin_amdgcn_mfma_f32_16x16x32_bf16(kf3, qf[0][3], acc0, 0, 0, 0); \
    acc1 = __builtin_amdgcn_mfma_f32_16x16x32_bf16(kf3, qf[1][3], acc1, 0, 0, 0); \
    const int jb = jw + (jtv) * 16;                                            \
    const f32x4 k2v = *(const f32x4*)(k2 + bh * 1024 + jb + quad * 4);         \
    const uchar4 m4 = *(const uchar4*)(bxb + jb + quad * 4);                   \
    const bool vj0 = (m4.x == 0), vj1 = (m4.y == 0);                           \
    const bool vj2 = (m4.z == 0), vj3 = (m4.w == 0);                           \
    f32x4 kc;                                                                  \
    kc[0] = a1l * k2v[0]; kc[1] = a1l * k2v[1];                                \
    kc[2] = a1l * k2v[2]; kc[3] = a1l * k2v[3];                                \
    {                                                                          \
        f32x4 ev;                                                              \
        ev[0] = (vi0 && vj0) ? exp2f(fminf(fmaf(a2l, acc0[0], cr0 - kc[0]), 86.56f)) : 1.0f; \
        ev[1] = (vi0 && vj1) ? exp2f(fminf(fmaf(a2l, acc0[1], cr0 - kc[1]), 86.56f)) : 1.0f; \
        ev[2] = (vi0 && vj2) ? exp2f(fminf(fmaf(a2l, acc0[2], cr0 - kc[2]), 86.56f)) : 1.0f; \
        ev[3] = (vi0 && vj3) ? exp2f(fminf(fmaf(a2l, acc0[3], cr0 - kc[3]), 86.56f)) : 1.0f; \
        *(f32x4*)&e_lds[lm][jb + quad * 4] = ev;                               \
        rsum0 += (ev[0] + ev[1]) + (ev[2] + ev[3]);                            \
    }                                                                          \
    {                                                                          \
        f32x4 ev;                                                              \
        ev[0] = (vi1 && vj0) ? exp2f(fminf(fmaf(a2l, acc1[0], cr1 - kc[0]), 86.56f)) : 1.0f; \
        ev[1] = (vi1 && vj1) ? exp2f(fminf(fmaf(a2l, acc1[1], cr1 - kc[1]), 86.56f)) : 1.0f; \
        ev[2] = (vi1 && vj2) ? exp2f(fminf(fmaf(a2l, acc1[2], cr1 - kc[2]), 86.56f)) : 1.0f; \
        ev[3] = (vi1 && vj3) ? exp2f(fminf(fmaf(a2l, acc1[3], cr1 - kc[3]), 86.56f)) : 1.0f; \
        *(f32x4*)&e_lds[16 + lm][jb + quad * 4] = ev;                          \
        rsum1 += (ev[0] + ev[1]) + (ev[2] + ev[3]);                            \
    }                                                                          \
} while (0)

// ---- FUSED: persistent blocks (1/CU, 256 = 8 XCD x 32 CU), 3 strips each.
// XCD-affine mapping: xcd = g&7 owns bh in {xcd, xcd+8, xcd+16} -> each
// XCD's L2 holds exactly 3 K slabs (1.5 MB). Named-register K double-buffer
// (static indices only — rule #20). exp2-folded BN. Store drain of strip s
// overlaps phase A of strip s+1.
__global__ __launch_bounds__(512, 1) void k_fused(
        const float* __restrict__ Q, const float* __restrict__ Km,
        const float* __restrict__ q2, const float* __restrict__ k2,
        const float* __restrict__ ac, const unsigned char* __restrict__ bx,
        float* __restrict__ co, float* __restrict__ wcolP) {
    const int g = blockIdx.x;             // 0..255
    const int xcd = g & 7, slot = g >> 3;
    const int t = threadIdx.x, lane = t & 63, w = t >> 6;   // 8 waves
    const int lm = lane & 15, quad = lane >> 4;
    const int jw = w * 128;               // wave's 128-col range

    __shared__ float e_lds[32][1028];     // padded: balanced LDS banks
    __shared__ float rowsum[3][32];       // one slot per rep (no reset races)
    if (t < 96) ((float*)rowsum)[t] = 0.f;
    __syncthreads();

#pragma unroll 1
    for (int rep = 0; rep < 3; rep++) {
        const int idx = slot * 3 + rep;   // 0..95 within this XCD
        const int bh = xcd + ((idx >> 5) << 3);
        const int strip = idx & 31;
        const int b = bh / HH, h = bh - b * HH;
        const int i0 = strip * 32;
        const float* Qb = Q + (size_t)b * LL * DD + h * DHH;
        const float* Kb = Km + (size_t)b * LL * DD + h * DHH;
        const float a1 = ac[h], c1 = ac[8 + h];
        const unsigned char* bxb = bx + b * LL;
        const float a1l = a1 * LOG2E;
        const float a2l = 2.0f * a1l;
        const float c1l = c1 * LOG2E;

        // Q fragments (B-operand): two row-sets i0+s*16+lm, k-chunks by quad
        short8 qf[2][4];
#pragma unroll
        for (int s = 0; s < 2; s++)
#pragma unroll
            for (int kk = 0; kk < 4; kk++)
                qf[s][kk] = ld_bf8(Qb + (size_t)(i0 + s * 16 + lm) * DD + kk * 32 + quad * 8);

        const bool vi0 = (bxb[i0 + lm] == 0);
        const bool vi1 = (bxb[i0 + 16 + lm] == 0);
        const float cr0 = c1l - a1l * q2[bh * 1024 + i0 + lm];
        const float cr1 = c1l - a1l * q2[bh * 1024 + i0 + 16 + lm];

        // named K double-buffers (registers — static indices only)
        float4 rA0, rA1, rA2, rA3, rA4, rA5, rA6, rA7;
        float4 rB0, rB1, rB2, rB3, rB4, rB5, rB6, rB7;

        float rsum0 = 0.f, rsum1 = 0.f;
        KLOAD(rA, 0);
        KLOAD(rB, 1);
        KCOMP(rA, 0);
        KLOAD(rA, 2);
        KCOMP(rB, 1);
        KLOAD(rB, 3);
        KCOMP(rA, 2);
        KLOAD(rA, 4);
        KCOMP(rB, 3);
        KLOAD(rB, 5);
        KCOMP(rA, 4);
        KLOAD(rA, 6);
        KCOMP(rB, 5);
        KLOAD(rB, 7);
        KCOMP(rA, 6);
        KCOMP(rB, 7);

        // row-sum: reduce over quads, then across waves via LDS atomics
        rsum0 += __shfl_xor(rsum0, 16);
        rsum0 += __shfl_xor(rsum0, 32);
        rsum1 += __shfl_xor(rsum1, 16);
        rsum1 += __shfl_xor(rsum1, 32);
        if (lane < 16) {
            atomicAdd(&rowsum[rep][lm], rsum0);
            atomicAdd(&rowsum[rep][16 + lm], rsum1);
        }
        __syncthreads();

        // phase B: coalesced scaled NT stores + half-strip col sums
        const int cg = t & 255, rh = t >> 8;
        float* cob = co + ((size_t)bh << 20) + (size_t)(i0 + rh * 16) * 1024 + cg * 4;
        float* wp = wcolP + ((size_t)((strip * 2 + rh) * 24 + bh)) * 1024 + cg * 4;
        float cs0 = 0.f, cs1 = 0.f, cs2 = 0.f, cs3 = 0.f;
#pragma unroll
        for (int rr = 0; rr < 16; rr++) {
            const int r = rh * 16 + rr;
            const float inv = 1.0f / rowsum[rep][r];
            f32x4 v = *(const f32x4*)&e_lds[r][cg * 4];
            v[0] *= inv; v[1] *= inv; v[2] *= inv; v[3] *= inv;
            __builtin_nontemporal_store(v, (f32x4*)(cob + (size_t)rr * 1024));
            cs0 += v[0]; cs1 += v[1]; cs2 += v[2]; cs3 += v[3];
        }
        f32x4 wv; wv[0] = cs0; wv[1] = cs1; wv[2] = cs2; wv[3] = cs3;
        *(f32x4*)wp = wv;
        __syncthreads();   // e_lds free for next rep (stores already issued)
    }
}

// ---- reduce col-sum half-strip partials -> wcol; fused BN2 block partials
__global__ void k_wcol_reduce(const float* __restrict__ wcolP,
                              float* __restrict__ wcol, float* __restrict__ ws2) {
    const int t = threadIdx.x;
    int g = blockIdx.x * 256 + t;                    // 24576
    float s = 0.f;
#pragma unroll 8
    for (int strip = 0; strip < 64; strip++)
        s += wcolP[(size_t)strip * 24576 + g];
    wcol[g] = s;
    float a = s, b = s * s;
#pragma unroll
    for (int off = 1; off < 64; off <<= 1) { a += __shfl_xor(a, off); b += __shfl_xor(b, off); }
    __shared__ float sc[4][2];
    if ((t & 63) == 0) { sc[t >> 6][0] = a; sc[t >> 6][1] = b; }
    __syncthreads();
    if (t == 0) {
        ws2[blockIdx.x * 2]     = sc[0][0] + sc[1][0] + sc[2][0] + sc[3][0];
        ws2[blockIdx.x * 2 + 1] = sc[0][1] + sc[1][1] + sc[2][1] + sc[3][1];
    }
}

// ------- tail: BN2 (from block partials) + gate + per-batch softmax
__global__ __launch_bounds__(1024) void k_tail(
        const float* __restrict__ wcol, const float* __restrict__ ws2,
        const unsigned char* __restrict__ bx,
        const float* __restrict__ g2, const float* __restrict__ b2,
        const float* __restrict__ Wp, const float* __restrict__ bp,
        float* __restrict__ wout) {
    const int t = threadIdx.x, lane = t & 63, wv = t >> 6;
    __shared__ float abuf[12];       // a2s[0..5], c2s[6..11]
    __shared__ float xb[4096];
    __shared__ float wred[16][2];

    if (t < HH) {
        float s = 0.f, s2 = 0.f;
        for (int b = 0; b < 4; b++) {
            int bh = b * HH + t;
#pragma unroll
            for (int sub = 0; sub < 4; sub++) {
                int blk = bh * 4 + sub;
                s += ws2[blk * 2];
                s2 += ws2[blk * 2 + 1];
            }
        }
        float m = s / 4096.f;
        float var = fmaxf(s2 / 4096.f - m * m, 0.0f);
        float r = rsqrtf(var + EPS);
        float a = r * g2[t];
        abuf[t] = a;
        abuf[6 + t] = b2[t] - m * a;
    }
    __syncthreads();

    const float bp0 = bp[0], bp1 = bp[1];
#pragma unroll
    for (int p = 0; p < 4; p++) {
        int idx = t + p * 1024;
        int b = idx >> 10, l = idx & 1023;
        float z0 = bp0, z1 = bp1;
#pragma unroll
        for (int h = 0; h < HH; h++) {
            float wn = abuf[h] * wcol[(size_t)(b * HH + h) * 1024 + l] + abuf[6 + h];
            z0 += wn * Wp[h];
            z1 += wn * Wp[HH + h];
        }
        float pc = 1.0f / (1.0f + __expf(z1 - z0));
        xb[idx] = bx[b * LL + l] ? -INFINITY : pc;
    }
    __syncthreads();

    const int bb = t >> 8, tb = t & 255;
    float4 xv = *(const float4*)&xb[bb * 1024 + tb * 4];
    float mx = fmaxf(fmaxf(xv.x, xv.y), fmaxf(xv.z, xv.w));
#pragma unroll
    for (int off = 1; off < 64; off <<= 1) mx = fmaxf(mx, __shfl_xor(mx, off));
    if (lane == 0) wred[wv][0] = mx;
    __syncthreads();
    mx = fmaxf(fmaxf(wred[bb * 4][0], wred[bb * 4 + 1][0]),
               fmaxf(wred[bb * 4 + 2][0], wred[bb * 4 + 3][0]));
    float e0 = __expf(xv.x - mx), e1 = __expf(xv.y - mx);
    float e2 = __expf(xv.z - mx), e3 = __expf(xv.w - mx);
    float ss = e0 + e1 + e2 + e3;
#pragma unroll
    for (int off = 1; off < 64; off <<= 1) ss += __shfl_xor(ss, off);
    if (lane == 0) wred[wv][1] = ss;
    __syncthreads();
    float sum = wred[bb * 4][1] + wred[bb * 4 + 1][1] + wred[bb * 4 + 2][1] + wred[bb * 4 + 3][1];
    float4 o;
    o.x = e0 / sum; o.y = e1 / sum; o.z = e2 / sum; o.w = e3 / sum;
    *(float4*)&wout[bb * 1024 + tb * 4] = o;
}

extern "C" void kernel_launch(void* const* d_in, const int* in_sizes, int n_in,
                              void* d_out, int out_size, void* d_ws, size_t ws_size,
                              hipStream_t stream) {
    const float* Q  = (const float*)d_in[0];
    const float* K  = (const float*)d_in[1];
    const float* V  = (const float*)d_in[2];
    // d_in[3] = pad_mask — derivable from bx_packed, unused
    const unsigned char* bx = (const unsigned char*)d_in[4];
    const float* g1 = (const float*)d_in[5];
    const float* b1 = (const float*)d_in[6];
    const float* g2 = (const float*)d_in[7];
    const float* b2 = (const float*)d_in[8];
    const float* Wp = (const float*)d_in[9];
    const float* bp = (const float*)d_in[10];

    float* out  = (float*)d_out;
    float* co   = out;                        // (B,H,L,L)
    float* wout = out + CO_ELEMS;             // (B,L,1)
    float* vh   = out + CO_ELEMS + W_ELEMS;   // (B,H,L,DH)

    float* ws = (float*)d_ws;                 // ~21.2 MB
    float* q2     = ws + OFF_Q2;
    float* k2     = ws + OFF_K2;
    float* wcol   = ws + OFF_WC;
    float* statsP = ws + OFF_SP;
    float* ac     = ws + OFF_AC;
    float* ws2    = ws + OFF_SS;
    float* wcolP  = ws + OFF_WP;
    float* gramP  = ws + OFF_GP;
    float* ms1    = ws + OFF_MS1;
    float* ms2    = ws + OFF_MS2;

    k_gram<<<dim3(8, 24, 3), 256, 0, stream>>>(Q, K, V, ws, gramP, ms1, ms2, vh);
    k_stats3<<<24, 1024, 0, stream>>>(ms1, ms2, gramP, q2, k2, statsP);
    k_stats2<<<1, 64, 0, stream>>>(statsP, g1, b1, ac);
    k_fused<<<256, 512, 0, stream>>>(Q, K, q2, k2, ac, bx, co, wcolP);
    k_wcol_reduce<<<96, 256, 0, stream>>>(wcolP, wcol, ws2);
    k_tail<<<1, 1024, 0, stream>>>(wcol, ws2, bx, g2, b2, Wp, bp, wout);
}